// Round 11
// baseline (109.058 us; speedup 1.0000x reference)
//
#include <hip/hip_runtime.h>
#include <math.h>

#define NB 8192
#define ND 128            // elements (bytes in fp8) per row
#define GSTEP 64          // j rows per step
#define NSTEP 8           // steps per wave -> 512 j per wave
#define NJB 16            // j-groups (8192 / 512)

// (log2 e)^2 folded into the squared-norm terms: sqrt(c2*sq) = d*log2e = d2,
// so exp(-d) = 2^(-d2).
#define C2F 2.0813689810056077f
#define NC2 (-4.1627379620112154f)   // -2*c2, fma coefficient on dot
// Schraudolph exp2: 2^(-d2) ~= as_float((int)(2^23*(-d2 + 127 - 0.05756)))
// piecewise-linear-in-mantissa; offset mean-centers the (1+f)*2^-f error
// (range -3.9%..+2.0%, mean ~0 over frac-uniform inputs -> lse bias ~0).
#define SCH_A (-8388608.0f)          // -2^23
#define SCH_B 1064870050.0f          // (127 - 0.05756) * 2^23

typedef float f32x4 __attribute__((ext_vector_type(4)));
typedef unsigned long long ull;

// prep: 16 threads per row, each owns one 8-byte fp8 chunk.
// Emits fp8 e4m3 in MFMA fragment-major layout (8-B units):
//   idx = (row>>4)*256 + kk*64 + hi*16 + (row&15),  kk=chunk>>2, hi=chunk&3
// Also: c2-scaled ||sk||^2/||im||^2 (fp32), diag = ||sk-im|| (fp32),
// rowsum zero, ticket zero.
__global__ void __launch_bounds__(256) prep_kernel(
    const float* __restrict__ sk, const float* __restrict__ im,
    ull* __restrict__ skf, ull* __restrict__ imf,
    float* __restrict__ skn, float* __restrict__ imn,
    float* __restrict__ diag, float* __restrict__ rowsum,
    unsigned* __restrict__ ticket) {
    if (blockIdx.x == 0 && threadIdx.x == 0) *ticket = 0u;
    const int gtid = blockIdx.x * 256 + threadIdx.x;
    const int row = gtid >> 4;          // 0..8191
    const int j = gtid & 15;            // 8-B chunk index
    const size_t off = (size_t)row * ND + j * 8;
    const float4* a4 = reinterpret_cast<const float4*>(sk + off);
    const float4* b4 = reinterpret_cast<const float4*>(im + off);
    float4 a0 = a4[0], a1 = a4[1], b0 = b4[0], b1 = b4[1];

    unsigned al = 0, ah = 0, bl = 0, bh = 0;
    al = __builtin_amdgcn_cvt_pk_fp8_f32(a0.x, a0.y, al, false);
    al = __builtin_amdgcn_cvt_pk_fp8_f32(a0.z, a0.w, al, true);
    ah = __builtin_amdgcn_cvt_pk_fp8_f32(a1.x, a1.y, ah, false);
    ah = __builtin_amdgcn_cvt_pk_fp8_f32(a1.z, a1.w, ah, true);
    bl = __builtin_amdgcn_cvt_pk_fp8_f32(b0.x, b0.y, bl, false);
    bl = __builtin_amdgcn_cvt_pk_fp8_f32(b0.z, b0.w, bl, true);
    bh = __builtin_amdgcn_cvt_pk_fp8_f32(b1.x, b1.y, bh, false);
    bh = __builtin_amdgcn_cvt_pk_fp8_f32(b1.z, b1.w, bh, true);

    const size_t didx = (size_t)(row >> 4) * 256 + (j >> 2) * 64 + (j & 3) * 16 + (row & 15);
    skf[didx] = (ull)al | ((ull)ah << 32);
    imf[didx] = (ull)bl | ((ull)bh << 32);

    float sa = a0.x*a0.x + a0.y*a0.y + a0.z*a0.z + a0.w*a0.w
             + a1.x*a1.x + a1.y*a1.y + a1.z*a1.z + a1.w*a1.w;
    float sb = b0.x*b0.x + b0.y*b0.y + b0.z*b0.z + b0.w*b0.w
             + b1.x*b1.x + b1.y*b1.y + b1.z*b1.z + b1.w*b1.w;
    float d0 = a0.x-b0.x, d1 = a0.y-b0.y, d2 = a0.z-b0.z, d3 = a0.w-b0.w;
    float d4 = a1.x-b1.x, d5 = a1.y-b1.y, d6 = a1.z-b1.z, d7 = a1.w-b1.w;
    float sd = d0*d0 + d1*d1 + d2*d2 + d3*d3 + d4*d4 + d5*d5 + d6*d6 + d7*d7;
#pragma unroll
    for (int st = 1; st < 16; st <<= 1) {
        sa += __shfl_xor(sa, st);
        sb += __shfl_xor(sb, st);
        sd += __shfl_xor(sd, st);
    }
    if (j == 0) {
        skn[row] = sa * C2F;
        imn[row] = sb * C2F;
        diag[row] = sqrtf(sd);
    } else if (j == 1) {
        rowsum[row] = 0.f;
    }
}

// tile: barrier-free, LDS-free, fused finalize. Each wave: 32 i-cols x 512 j
// (8 staggered steps of 64 j). Fragments read directly from fragment-major
// fp8 arrays (L2-resident, coalesced 8 B/lane). In-step af ping-pong: loads
// for kk+1 (or next step's kk=0) issue before MFMA(kk), so load latency
// hides under MFMA + epilogue. Epilogue: sqrt (exact trans) + Schraudolph
// exp2 (fma+cvt, no trans). Row sums -> device atomicAdd into rowsum;
// last block (ticket) computes mean(log(rowsum)+diag) -> out.
__global__ void __launch_bounds__(256, 4) tile_kernel(
    const ull* __restrict__ skf, const ull* __restrict__ imf,
    const float* __restrict__ skn, const float* __restrict__ imn,
    const float* __restrict__ diag, float* __restrict__ rowsum,
    unsigned* __restrict__ ticket, float* __restrict__ out) {
    const int w = threadIdx.x >> 6, lane = threadIdx.x & 63;
    const int hi = lane >> 4, lo = lane & 15;
    const int gw = blockIdx.x * 4 + w;       // 0..4095
    const int iw = (gw & 255) * 32;          // wave's 32 i columns
    const int jgrp = gw >> 8;                // 0..15
    const int phase = (w << 1) & (NSTEP - 1);    // stagger waves on a SIMD
    const size_t gbase = (size_t)jgrp * 8192;    // 8-B units: jgrp*512 rows

    // Persistent B (sk) fragments + c2-scaled sk norms.
    long bfr[2][4];
    const int gi = iw >> 4;
#pragma unroll
    for (int n = 0; n < 2; ++n)
#pragma unroll
        for (int kk = 0; kk < 4; ++kk)
            bfr[n][kk] = (long)skf[(size_t)(gi + n) * 256 + kk * 64 + lane];
    float skv[2];
    skv[0] = skn[iw + lo];
    skv[1] = skn[iw + 16 + lo];

    float sacc[2] = {0.f, 0.f};

    // Preload af buffer 0: kk=0 fragments of the first (staggered) step.
    long af[2][4];
#pragma unroll
    for (int m = 0; m < 4; ++m)
        af[0][m] = (long)imf[gbase + (size_t)phase * 1024 + (size_t)m * 256 + lane];

    for (int s0 = 0; s0 < NSTEP; ++s0) {
        const int s = (s0 + phase) & (NSTEP - 1);
        const int sn = (s0 + 1 + phase) & (NSTEP - 1);   // wraps on last iter (harmless)
        const int jb = jgrp * (GSTEP * NSTEP) + s * GSTEP;
        const size_t ga = gbase + (size_t)s * 1024;
        const size_t gan = gbase + (size_t)sn * 1024;

        // im norms for this step (j = jb + m*16 + hi*4 + r) — issued early.
        float imnv[4][4];
#pragma unroll
        for (int m = 0; m < 4; ++m) {
            float4 v = *reinterpret_cast<const float4*>(imn + jb + m * 16 + hi * 4);
            imnv[m][0] = v.x; imnv[m][1] = v.y; imnv[m][2] = v.z; imnv[m][3] = v.w;
        }

        f32x4 acc[4][2];
#pragma unroll
        for (int m = 0; m < 4; ++m)
#pragma unroll
            for (int n = 0; n < 2; ++n)
                acc[m][n] = (f32x4){0.f, 0.f, 0.f, 0.f};

#pragma unroll
        for (int kk = 0; kk < 4; ++kk) {
            const int cur = kk & 1, nxt = cur ^ 1;
            // Prefetch: kk+1 of this step, or kk=0 of the next step.
            const size_t pga = (kk < 3) ? (ga + (size_t)(kk + 1) * 64) : gan;
#pragma unroll
            for (int m = 0; m < 4; ++m)
                af[nxt][m] = (long)imf[pga + (size_t)m * 256 + lane];
#pragma unroll
            for (int m = 0; m < 4; ++m)
#pragma unroll
                for (int n = 0; n < 2; ++n)
                    acc[m][n] = __builtin_amdgcn_mfma_f32_16x16x32_fp8_fp8(
                        af[cur][m], bfr[n][kk], acc[m][n], 0, 0, 0);
        }

        // Epilogue: i fixed per n (col = lo); j = jb + m*16 + hi*4 + r.
        // d2 = sqrt(c2*d^2) = d*log2e;  e = 2^-d2 via Schraudolph (no trans).
#pragma unroll
        for (int n = 0; n < 2; ++n) {
            float ssum = 0.f;
#pragma unroll
            for (int m = 0; m < 4; ++m) {
#pragma unroll
                for (int r = 0; r < 4; ++r) {
                    float sq2 = fmaf(NC2, acc[m][n][r], skv[n]) + imnv[m][r];
                    float d2;
                    asm("v_sqrt_f32 %0, abs(%1)" : "=v"(d2) : "v"(sq2));
                    float tt = fmaf(d2, SCH_A, SCH_B);
                    float e = __int_as_float((int)tt);
                    ssum += e;
                }
            }
            sacc[n] += ssum;
        }
    }

    // Fold hi groups (j-partitions); one atomicAdd per i-column (device scope).
#pragma unroll
    for (int n = 0; n < 2; ++n) {
        sacc[n] += __shfl_xor(sacc[n], 16);
        sacc[n] += __shfl_xor(sacc[n], 32);
    }
    if (lane < 16) {
        atomicAdd(&rowsum[iw + lo], sacc[0]);
        atomicAdd(&rowsum[iw + 16 + lo], sacc[1]);
    }

    // Ticket: last block computes loss = mean(log(rowsum) + diag).
    __shared__ unsigned lastFlag;
    __shared__ float red[256];
    __syncthreads();
    if (threadIdx.x == 0) {
        __threadfence();
        lastFlag = (atomicAdd(ticket, 1u) == (unsigned)(gridDim.x - 1)) ? 1u : 0u;
    }
    __syncthreads();
    if (lastFlag) {
        __threadfence();
        float s = 0.f;
        for (int r = threadIdx.x; r < NB; r += 256) {
            float rs = atomicAdd(&rowsum[r], 0.0f);   // device-coherent read
            s += __logf(rs) + diag[r];
        }
        red[threadIdx.x] = s;
        __syncthreads();
        for (int st = 128; st > 0; st >>= 1) {
            if (threadIdx.x < st) red[threadIdx.x] += red[threadIdx.x + st];
            __syncthreads();
        }
        if (threadIdx.x == 0) out[0] = red[0] / (float)NB;
    }
}

extern "C" void kernel_launch(void* const* d_in, const int* in_sizes, int n_in,
                              void* d_out, int out_size, void* d_ws, size_t ws_size,
                              hipStream_t stream) {
    const float* sk = (const float*)d_in[0];
    const float* im = (const float*)d_in[1];
    float* out = (float*)d_out;
    float* ws = (float*)d_ws;

    ull* skf = (ull*)ws;                                    // NB*128 fp8, frag-major (1 MB)
    ull* imf = skf + (size_t)NB * ND / 8;                   // (1 MB)
    float* fbase  = ws + (size_t)NB * ND / 2;               // 2 MB consumed above
    float* skn    = fbase;                                  // [NB] (c2-scaled)
    float* imn    = fbase + NB;                             // [NB] (c2-scaled)
    float* diag   = fbase + 2 * NB;                         // [NB]
    float* rowsum = fbase + 3 * NB;                         // [NB]
    unsigned* ticket = (unsigned*)(fbase + 4 * NB);         // [1]

    prep_kernel<<<NB * 16 / 256, 256, 0, stream>>>(
        sk, im, skf, imf, skn, imn, diag, rowsum, ticket);
    tile_kernel<<<1024, 256, 0, stream>>>(
        skf, imf, skn, imn, diag, rowsum, ticket, out);
}

// Round 12
// 86.760 us; speedup vs baseline: 1.2570x; 1.2570x over previous
//
#include <hip/hip_runtime.h>
#include <math.h>

#define NB 8192
#define ND 128            // elements (bytes in fp8) per row
#define GSTEP 64          // j rows per step
#define NSTEP 8           // steps per wave -> 512 j per wave
#define NJB 16            // j-groups (8192 / 512)

// (log2 e)^2 folded into the squared-norm terms: sqrt(c2*sq) = d*log2e = d2,
// so exp(-d) = 2^(-d2).
#define C2F 2.0813689810056077f
#define NC2 (-4.1627379620112154f)   // -2*c2, fma coefficient on dot
// Schraudolph exp2: 2^(-d2) ~= as_float((int)fma(d2, -2^23, (127-0.05756)*2^23))
// (validated in R11: passed with absmax 0.0 vs np reference)
#define SCH_A (-8388608.0f)          // -2^23
#define SCH_B 1064870050.0f          // (127 - 0.05756) * 2^23

typedef float f32x4 __attribute__((ext_vector_type(4)));
typedef unsigned long long ull;

// prep: 16 threads per row, each owns one 8-byte fp8 chunk (k = j*8..j*8+8).
// Emits fp8 e4m3 in MFMA FRAGMENT-MAJOR layout (8-B units):
//   idx = (row>>4)*256 + kk*64 + hi*16 + (row&15),  kk=j>>2, hi=j&3
// so a wave's fragment load in tile is one coalesced 512-B global load.
// Also: c2-scaled ||sk||^2 / ||im||^2 (fp32), diag = ||sk-im|| (fp32).
__global__ void __launch_bounds__(256) prep_kernel(
    const float* __restrict__ sk, const float* __restrict__ im,
    ull* __restrict__ skf, ull* __restrict__ imf,
    float* __restrict__ skn, float* __restrict__ imn,
    float* __restrict__ diag, float* __restrict__ gacc,
    unsigned* __restrict__ ticket) {
    if (blockIdx.x == 0 && threadIdx.x == 0) { *gacc = 0.f; *ticket = 0u; }
    const int gtid = blockIdx.x * 256 + threadIdx.x;
    const int row = gtid >> 4;          // 0..8191
    const int j = gtid & 15;            // 8-B chunk index
    const size_t off = (size_t)row * ND + j * 8;
    const float4* a4 = reinterpret_cast<const float4*>(sk + off);
    const float4* b4 = reinterpret_cast<const float4*>(im + off);
    float4 a0 = a4[0], a1 = a4[1], b0 = b4[0], b1 = b4[1];

    unsigned al = 0, ah = 0, bl = 0, bh = 0;
    al = __builtin_amdgcn_cvt_pk_fp8_f32(a0.x, a0.y, al, false);
    al = __builtin_amdgcn_cvt_pk_fp8_f32(a0.z, a0.w, al, true);
    ah = __builtin_amdgcn_cvt_pk_fp8_f32(a1.x, a1.y, ah, false);
    ah = __builtin_amdgcn_cvt_pk_fp8_f32(a1.z, a1.w, ah, true);
    bl = __builtin_amdgcn_cvt_pk_fp8_f32(b0.x, b0.y, bl, false);
    bl = __builtin_amdgcn_cvt_pk_fp8_f32(b0.z, b0.w, bl, true);
    bh = __builtin_amdgcn_cvt_pk_fp8_f32(b1.x, b1.y, bh, false);
    bh = __builtin_amdgcn_cvt_pk_fp8_f32(b1.z, b1.w, bh, true);

    const size_t didx = (size_t)(row >> 4) * 256 + (j >> 2) * 64 + (j & 3) * 16 + (row & 15);
    skf[didx] = (ull)al | ((ull)ah << 32);
    imf[didx] = (ull)bl | ((ull)bh << 32);

    float sa = a0.x*a0.x + a0.y*a0.y + a0.z*a0.z + a0.w*a0.w
             + a1.x*a1.x + a1.y*a1.y + a1.z*a1.z + a1.w*a1.w;
    float sb = b0.x*b0.x + b0.y*b0.y + b0.z*b0.z + b0.w*b0.w
             + b1.x*b1.x + b1.y*b1.y + b1.z*b1.z + b1.w*b1.w;
    float d0 = a0.x-b0.x, d1 = a0.y-b0.y, d2 = a0.z-b0.z, d3 = a0.w-b0.w;
    float d4 = a1.x-b1.x, d5 = a1.y-b1.y, d6 = a1.z-b1.z, d7 = a1.w-b1.w;
    float sd = d0*d0 + d1*d1 + d2*d2 + d3*d3 + d4*d4 + d5*d5 + d6*d6 + d7*d7;
#pragma unroll
    for (int st = 1; st < 16; st <<= 1) {   // 16-lane groups = one row
        sa += __shfl_xor(sa, st);
        sb += __shfl_xor(sb, st);
        sd += __shfl_xor(sd, st);
    }
    if (j == 0) {
        skn[row] = sa * C2F;
        imn[row] = sb * C2F;
        diag[row] = sqrtf(sd);
    }
}

// tile: barrier-free, LDS-free (identical structure to the 87.5 µs R10 build).
// Each wave owns 32 i-cols x 512 j-rows (8 steps of 64 j). All MFMA
// fragments read DIRECTLY from the fragment-major fp8 arrays with
// fully-coalesced 8 B/lane loads (L2-resident). Epilogue: exact v_sqrt +
// Schraudolph exp2 (fma+cvt, no trans) — the single change vs R10.
__global__ void __launch_bounds__(256, 4) tile_kernel(
    const ull* __restrict__ skf, const ull* __restrict__ imf,
    const float* __restrict__ skn, const float* __restrict__ imn,
    float* __restrict__ partial) {
    const int w = threadIdx.x >> 6, lane = threadIdx.x & 63;
    const int hi = lane >> 4, lo = lane & 15;
    const int gw = blockIdx.x * 4 + w;       // 0..4095
    const int iw = (gw & 255) * 32;          // wave's 32 i columns
    const int jgrp = gw >> 8;                // 0..15
    const int jg0 = jgrp * (GSTEP * NSTEP);  // wave's j base

    // Persistent B (sk) fragments + c2-scaled sk norms.
    long bfr[2][4];
    const int gi = iw >> 4;
#pragma unroll
    for (int n = 0; n < 2; ++n)
#pragma unroll
        for (int kk = 0; kk < 4; ++kk)
            bfr[n][kk] = (long)skf[(size_t)(gi + n) * 256 + kk * 64 + lane];
    float skv[2];
    skv[0] = skn[iw + lo];
    skv[1] = skn[iw + 16 + lo];

    float sacc[2] = {0.f, 0.f};

    for (int s = 0; s < NSTEP; ++s) {
        const int jb = jg0 + s * GSTEP;
        const size_t ga = (size_t)(jb >> 4) * 256;

        // c2-scaled im norms for this step (j = jb + m*16 + hi*4 + r).
        float imnv[4][4];
#pragma unroll
        for (int m = 0; m < 4; ++m) {
            float4 v = *reinterpret_cast<const float4*>(imn + jb + m * 16 + hi * 4);
            imnv[m][0] = v.x; imnv[m][1] = v.y; imnv[m][2] = v.z; imnv[m][3] = v.w;
        }

        f32x4 acc[4][2];
#pragma unroll
        for (int m = 0; m < 4; ++m)
#pragma unroll
            for (int n = 0; n < 2; ++n)
                acc[m][n] = (f32x4){0.f, 0.f, 0.f, 0.f};

#pragma unroll
        for (int kk = 0; kk < 4; ++kk) {
            long af[4];
#pragma unroll
            for (int m = 0; m < 4; ++m)
                af[m] = (long)imf[ga + (size_t)m * 256 + kk * 64 + lane];
#pragma unroll
            for (int m = 0; m < 4; ++m)
#pragma unroll
                for (int n = 0; n < 2; ++n)
                    acc[m][n] = __builtin_amdgcn_mfma_f32_16x16x32_fp8_fp8(
                        af[m], bfr[n][kk], acc[m][n], 0, 0, 0);
        }

        // Epilogue: i fixed per n (col = lo); j = jb + m*16 + hi*4 + r.
        // d2 = sqrt(c2*d^2) = d*log2e;  e = 2^-d2 via Schraudolph (fma+cvt).
#pragma unroll
        for (int n = 0; n < 2; ++n) {
            float ssum = 0.f;
#pragma unroll
            for (int m = 0; m < 4; ++m) {
#pragma unroll
                for (int r = 0; r < 4; ++r) {
                    float sq2 = fmaf(NC2, acc[m][n][r], skv[n]) + imnv[m][r];
                    float d2;
                    asm("v_sqrt_f32 %0, abs(%1)" : "=v"(d2) : "v"(sq2));
                    float tt = fmaf(d2, SCH_A, SCH_B);
                    ssum += __int_as_float((int)tt);
                }
            }
            sacc[n] += ssum;
        }
    }

    // Fold the hi groups (j-partitions); write this wave's 32 partials.
#pragma unroll
    for (int n = 0; n < 2; ++n) {
        sacc[n] += __shfl_xor(sacc[n], 16);
        sacc[n] += __shfl_xor(sacc[n], 32);
    }
    if (lane < 16) {
        partial[(size_t)jgrp * NB + iw + lo] = sacc[0];
        partial[(size_t)jgrp * NB + iw + 16 + lo] = sacc[1];
    }
}

// finalize: thread per row; 16 coalesced partial loads; log + diag; block
// reduce; device atomic + ticket, last block writes the mean.
__global__ void finalize_kernel(const float* __restrict__ partial,
                                const float* __restrict__ diag,
                                float* __restrict__ gacc, unsigned* __restrict__ ticket,
                                float* __restrict__ out) {
    const int i = blockIdx.x * 256 + threadIdx.x;
    float rs = 0.f;
#pragma unroll
    for (int c = 0; c < NJB; ++c) rs += partial[(size_t)c * NB + i];
    float v = __logf(rs) + diag[i];
    __shared__ float red[256];
    red[threadIdx.x] = v;
    __syncthreads();
    for (int st = 128; st > 0; st >>= 1) {
        if (threadIdx.x < st) red[threadIdx.x] += red[threadIdx.x + st];
        __syncthreads();
    }
    if (threadIdx.x == 0) {
        atomicAdd(gacc, red[0]);
        __threadfence();
        unsigned old = atomicAdd(ticket, 1u);
        if (old == (NB / 256) - 1) {
            float tot = atomicAdd(gacc, 0.f);   // device-coherent read
            out[0] = tot / (float)NB;
        }
    }
}

extern "C" void kernel_launch(void* const* d_in, const int* in_sizes, int n_in,
                              void* d_out, int out_size, void* d_ws, size_t ws_size,
                              hipStream_t stream) {
    const float* sk = (const float*)d_in[0];
    const float* im = (const float*)d_in[1];
    float* out = (float*)d_out;
    float* ws = (float*)d_ws;

    ull* skf = (ull*)ws;                                    // NB*128 fp8, frag-major (1 MB)
    ull* imf = skf + (size_t)NB * ND / 8;                   // (1 MB)
    float* fbase   = ws + (size_t)NB * ND / 2;              // 2 MB consumed above
    float* skn     = fbase;                                 // [NB] (c2-scaled)
    float* imn     = fbase + NB;                            // [NB] (c2-scaled)
    float* diag    = fbase + 2 * NB;                        // [NB]
    float* partial = fbase + 3 * NB;                        // [NJB][NB] (512 KB)
    float* gacc    = partial + (size_t)NJB * NB;            // [1]
    unsigned* ticket = (unsigned*)(gacc + 1);               // [1]

    prep_kernel<<<NB * 16 / 256, 256, 0, stream>>>(
        sk, im, skf, imf, skn, imn, diag, gacc, ticket);
    tile_kernel<<<1024, 256, 0, stream>>>(skf, imf, skn, imn, partial);
    finalize_kernel<<<NB / 256, 256, 0, stream>>>(partial, diag, gacc, ticket, out);
}